// Round 8
// baseline (295.066 us; speedup 1.0000x reference)
//
#include <hip/hip_runtime.h>
#include <stdint.h>

#define FC    256
#define HH    512
#define MX    1024
#define LASTN 128
#define NROW  16384
#define NGRP  2048

typedef unsigned short u16;
typedef __bf16 bf16x8 __attribute__((ext_vector_type(8)));
typedef float  f32x4  __attribute__((ext_vector_type(4)));

__device__ __forceinline__ float red16(float v) {
#pragma unroll
  for (int m = 1; m < 16; m <<= 1) v += __shfl_xor(v, m);
  return v;
}
// reduce across the 16 lanes sharing (lane & 3)
__device__ __forceinline__ float red16hi(float v) {
#pragma unroll
  for (int m = 4; m < 64; m <<= 1) v += __shfl_xor(v, m);
  return v;
}
__device__ __forceinline__ u16 to_bf16(float f) {
  unsigned u = __float_as_uint(f);
  return (u16)((u + 0x8000u) >> 16);
}
__device__ __forceinline__ float from_bf16(u16 s) {
  return __uint_as_float(((unsigned)s) << 16);
}
__device__ __forceinline__ uint32_t pk2(float a, float b) {
  return (uint32_t)to_bf16(a) | ((uint32_t)to_bf16(b) << 16);
}
__device__ __forceinline__ float tanh_fast(float x) {
  float e = __expf(2.f * x);
  return __fdividef(e - 1.f, e + 1.f);
}
__device__ __forceinline__ float sigmoid_fast(float x) {
  return __fdividef(1.f, 1.f + __expf(-x));
}
// async global->LDS, 16B per lane; LDS dest = wave-uniform base + lane*16
__device__ __forceinline__ void glds16(const void* g, void* l) {
  __builtin_amdgcn_global_load_lds(
      (__attribute__((address_space(1))) uint32_t*)g,
      (__attribute__((address_space(3))) uint32_t*)l, 16, 0, 0);
}
__device__ __forceinline__ bf16x8 frag_ld(const u16* p) {
  return __builtin_bit_cast(bf16x8, *(const uint4*)p);
}

// ============ k_prep: weights -> fragment-ordered bf16 global layout ============
// unit id = (u*NKC + kc)*64 + l ; contents j=0..7: W[kc*32+(l>>4)*8+j][u*16+(l&15)]
__global__ __launch_bounds__(256) void k_prep(
    const float* __restrict__ enc_w, const float* __restrict__ core_w,
    const float* __restrict__ ctx_w, const float* __restrict__ att1_w,
    const float* __restrict__ out_w,
    u16* __restrict__ encT, u16* __restrict__ uvT, u16* __restrict__ ctxT,
    u16* __restrict__ attT, u16* __restrict__ outT)
{
  const int bx = blockIdx.x, tid = threadIdx.x;
  const float* W; u16* D; int NKC, N, local; int uv = 0;
  if (bx < 64)       { W = enc_w;  D = encT; NKC = 16; N = 256; local = bx * 256 + tid; }
  else if (bx < 128) { W = core_w; D = uvT;  NKC = 8;  N = 256; local = (bx-64)*256 + tid; uv = 1; }
  else if (bx < 160) { W = ctx_w;  D = ctxT; NKC = 8;  N = 256; local = (bx-128)*256 + tid; }
  else if (bx < 176) { W = att1_w; D = attT; NKC = 8;  N = 128; local = (bx-160)*256 + tid; }
  else               { W = out_w;  D = outT; NKC = 48; N = 256; local = (bx-176)*256 + tid; }
  const int l  = local & 63;
  const int kc = (local >> 6) % NKC;
  const int u  = (local >> 6) / NKC;
  const int n  = u * 16 + (l & 15);
  const int k0 = kc * 32 + (l >> 4) * 8;
  float f[8];
#pragma unroll
  for (int j = 0; j < 8; ++j) {
    const int k = k0 + j;
    if (uv) f[j] = (n < 256) ? W[(size_t)k * 256 + n] : W[(size_t)(256 + k) * 256 + (n - 256)];
    else    f[j] = W[(size_t)k * N + n];
  }
  uint4 w;
  w.x = pk2(f[0], f[1]); w.y = pk2(f[2], f[3]);
  w.z = pk2(f[4], f[5]); w.w = pk2(f[6], f[7]);
  *(uint4*)&D[(size_t)local * 8] = w;
}

// ============ k_enc: s1 = relu(LN(state @ enc_w + b)) -> s1b ============
// tile 32 rows x 256 cols, 512 blocks; wave (rb=wv>>1, cb=wv&1); K=512 in pairs
__global__ __launch_bounds__(256) void k_enc(
    const float* __restrict__ state, const u16* __restrict__ encT,
    const float* __restrict__ enc_b, const float* __restrict__ enc_g,
    const float* __restrict__ enc_bb, u16* __restrict__ s1b)
{
  __shared__ __align__(16) u16 smA[2][128 * 8];     // 2 x 2 KB
  __shared__ __align__(16) u16 smB[2][16 * 64 * 8]; // 2 x 16 KB
  __shared__ float smP[2][2][16][2];
  const int tid = threadIdx.x, wv = tid >> 6, lane = tid & 63;
  const int cl = lane & 15, quad = lane >> 4;
  const int rb = wv >> 1, cb = wv & 1;
  const int row0 = blockIdx.x * 32;
  f32x4 acc[8];
#pragma unroll
  for (int u = 0; u < 8; ++u) acc[u] = (f32x4){0.f, 0.f, 0.f, 0.f};

  for (int kk = 0; kk < 8; ++kk) {
    __syncthreads();
    { // A: each thread stages unit (p=tid>>7, lu=tid&127), fp32 -> bf16
      const int p = tid >> 7, lu = tid & 127;
      const int kc = kk * 2 + p;
      const int rblk = lu >> 6, ll = lu & 63;
      const float* src = state + (size_t)(row0 + rblk * 16 + (ll & 15)) * HH + kc * 32 + (ll >> 4) * 8;
      float4 a = *(const float4*)src, b = *(const float4*)(src + 4);
      uint4 w; w.x = pk2(a.x, a.y); w.y = pk2(a.z, a.w); w.z = pk2(b.x, b.y); w.w = pk2(b.z, b.w);
      *(uint4*)&smA[p][(size_t)lu * 8] = w;
    }
#pragma unroll
    for (int p = 0; p < 2; ++p)
#pragma unroll
      for (int i = 0; i < 4; ++i) {
        const int u = wv * 4 + i;
        glds16(encT + ((size_t)(u * 16 + kk * 2 + p) * 64 + lane) * 8, &smB[p][u * 512]);
      }
    __syncthreads();
#pragma unroll
    for (int p = 0; p < 2; ++p) {
      bf16x8 af = frag_ld(&smA[p][(rb * 64 + lane) * 8]);
#pragma unroll
      for (int u = 0; u < 8; ++u) {
        bf16x8 bf = frag_ld(&smB[p][((cb * 8 + u) * 64 + lane) * 8]);
        acc[u] = __builtin_amdgcn_mfma_f32_16x16x32_bf16(af, bf, acc[u], 0, 0, 0);
      }
    }
  }
  float bias[8], gg[8], bb[8];
#pragma unroll
  for (int u = 0; u < 8; ++u) {
    const int col = cb * 128 + u * 16 + cl;
    bias[u] = enc_b[col]; gg[u] = enc_g[col]; bb[u] = enc_bb[col];
  }
  float vv[4][8];
#pragma unroll
  for (int r4 = 0; r4 < 4; ++r4) {
    float s = 0.f, sq = 0.f;
#pragma unroll
    for (int u = 0; u < 8; ++u) {
      float v = acc[u][r4] + bias[u];
      vv[r4][u] = v; s += v; sq += v * v;
    }
    s = red16(s); sq = red16(sq);
    if (cl == 0) { smP[cb][rb][quad * 4 + r4][0] = s; smP[cb][rb][quad * 4 + r4][1] = sq; }
  }
  __syncthreads();
#pragma unroll
  for (int r4 = 0; r4 < 4; ++r4) {
    const int rr = quad * 4 + r4;
    const float S  = smP[0][rb][rr][0] + smP[1][rb][rr][0];
    const float SQ = smP[0][rb][rr][1] + smP[1][rb][rr][1];
    const float mu = S * (1.f / 256.f);
    const float rs = rsqrtf(SQ * (1.f / 256.f) - mu * mu + 1e-5f);
    const int row = row0 + rb * 16 + rr;
#pragma unroll
    for (int u = 0; u < 8; ++u) {
      float o = fmaxf((vv[r4][u] - mu) * rs * gg[u] + bb[u], 0.f);
      s1b[(size_t)row * FC + cb * 128 + u * 16 + cl] = to_bf16(o);
    }
  }
}

// ============ k_pair: UV-compute + core-build + att/ctx GEMMs + epilogues ============
// v8: k_uv FUSED — each group's 8 UV rows are consumed only by this block, so we
// compute UV = s1[g*8..+8) @ uvT in-block: M=8(pad16), N=512, K=256; per wave
// 8 kc x {1 A-frag direct from s1b (L2), 8 B-frags direct from uvT (L2), 8 MFMA},
// barrier-free (att-pass pattern), acc -> smUV, 1 barrier. Deletes the k_uv kernel
// and the 67 MB UV round-trip. Rest identical to round-6 (measured 78.3us).
__global__ __launch_bounds__(256, 3) void k_pair(
    const u16* __restrict__ s1b, const u16* __restrict__ uvT,
    const float* __restrict__ core_b,
    const float* __restrict__ core_g, const float* __restrict__ core_bb,
    const u16* __restrict__ ctxT, const float* __restrict__ ctx_b,
    const float* __restrict__ ctx_g, const float* __restrict__ ctx_bb,
    const u16* __restrict__ attT, const float* __restrict__ att1_b,
    const float* __restrict__ att_g, const float* __restrict__ att_bb,
    const float* __restrict__ att2_w, const float* __restrict__ att2_b,
    u16* __restrict__ effb)
{
  __shared__ __align__(16) u16 smA[2048 * 8];     // 32 KB frag-ordered core; reused as smS
  __shared__ __align__(16) u16 smX[16 * 64 * 8];  // 16 KB: UV (f32), then ctx B staging
  __shared__ float att_s[64];
  float* smUV = (float*)smX;                      // 16 rows x 256 f32 (rows 0..7=U, 8..15=V)
  u16*   smB  = smX;                              // 16 units x 1 KB (ctx phase)
  const int g = blockIdx.x;
  const int tid = threadIdx.x, wv = tid >> 6, lane = tid & 63;
  const int cl = lane & 15, quad = lane >> 4;
  const int aswz = ((lane >> 5) & 1) << 2;        // A-frag read swizzle (bit5 -> bit2)

  // zero A (covers pad rows 56..63; swizzle is a bijection so full zero is safe)
#pragma unroll
  for (int i = 0; i < 8; ++i)
    *(uint4*)&smA[(size_t)(tid + i * 256) * 8] = (uint4){0u, 0u, 0u, 0u};

  // ---- UV compute pass: wave wv owns UV cols [wv*128, wv*128+128) ----
  {
    // A-frag rows: lane&15 (rows 8..15 are don't-care; clamp keeps reads in-bounds)
    const int rowA = min(g * 8 + (lane & 15), NROW - 1);
    const u16* aptr = s1b + (size_t)rowA * FC + (lane >> 4) * 8;
    f32x4 accU[8];
#pragma unroll
    for (int u = 0; u < 8; ++u) accU[u] = (f32x4){0.f, 0.f, 0.f, 0.f};
#pragma unroll 2
    for (int kc = 0; kc < 8; ++kc) {
      uint4 bfr[8];
#pragma unroll
      for (int u = 0; u < 8; ++u)
        bfr[u] = *(const uint4*)(uvT + ((size_t)((wv * 8 + u) * 8 + kc) * 64 + lane) * 8);
      bf16x8 af = frag_ld(aptr + kc * 32);
#pragma unroll
      for (int u = 0; u < 8; ++u) {
        bf16x8 bf = __builtin_bit_cast(bf16x8, bfr[u]);
        accU[u] = __builtin_amdgcn_mfma_f32_16x16x32_bf16(af, bf, accU[u], 0, 0, 0);
      }
    }
    // write rows 0..7 into smUV (col<256 -> U rows 0..7, col>=256 -> V rows 8..15)
#pragma unroll
    for (int r4 = 0; r4 < 4; ++r4) {
      const int r = quad * 4 + r4;
      if (r < 8) {
#pragma unroll
        for (int u = 0; u < 8; ++u) {
          const int c = wv * 128 + u * 16 + cl;
          const int rr = (c >> 8) * 8 + r;
          smUV[rr * 256 + (c & 255)] = accU[u][r4];
        }
      }
    }
  }
  __syncthreads();

  // ---- build core from LDS: 4 passes; wave covers 4 rows x 16 col-groups ----
  {
    const int s4  = lane & 3;        // row-within-4 (varies inside each 16-lane quarter)
    const int g16 = lane >> 2;       // column group 0..15
    const int c0  = g16 * 16;
    float4 CB[4], CG[4], CBB[4];     // CB[q] belongs to granule (q^s4) of this lane's window
#pragma unroll
    for (int q = 0; q < 4; ++q) {
      const int cq = c0 + ((q ^ s4) << 2);
      CB[q]  = *(const float4*)&core_b[cq];
      CG[q]  = *(const float4*)&core_g[cq];
      CBB[q] = *(const float4*)&core_bb[cq];
    }
#pragma unroll
    for (int it = 0; it < 4; ++it) {
      const int p = it * 16 + wv * 4 + s4;   // wave-uniform branch: 56 = it3,wv2,s4=0
      if (p < 56) {
        const int i = p / 7, t = p - i * 7;
        const int j = t + (t >= i ? 1 : 0);
        const float* uA = &smUV[i * 256 + c0];
        const float* vB = &smUV[(8 + j) * 256 + c0];
        float v[16];
        float s = 0.f, sq = 0.f;
#pragma unroll
        for (int q = 0; q < 4; ++q) {
          const int qo = (q ^ s4) << 2;      // XOR-rotated chunk order: conflict-free reads
          float4 ua = *(const float4*)(uA + qo);
          float4 vb = *(const float4*)(vB + qo);
          float x0 = ua.x + vb.x + CB[q].x, x1 = ua.y + vb.y + CB[q].y;
          float x2 = ua.z + vb.z + CB[q].z, x3 = ua.w + vb.w + CB[q].w;
          v[q*4+0] = x0; v[q*4+1] = x1; v[q*4+2] = x2; v[q*4+3] = x3;
          s += x0 + x1 + x2 + x3;
          sq += x0*x0 + x1*x1 + x2*x2 + x3*x3;
        }
        s = red16hi(s); sq = red16hi(sq);
        const float mu = s * (1.f / 256.f);
        const float rs = rsqrtf(sq * (1.f / 256.f) - mu * mu + 1e-5f);
#pragma unroll
        for (int q = 0; q < 4; ++q) {
          v[q*4+0] = fmaxf((v[q*4+0] - mu) * rs * CG[q].x + CBB[q].x, 0.f);
          v[q*4+1] = fmaxf((v[q*4+1] - mu) * rs * CG[q].y + CBB[q].y, 0.f);
          v[q*4+2] = fmaxf((v[q*4+2] - mu) * rs * CG[q].z + CBB[q].z, 0.f);
          v[q*4+3] = fmaxf((v[q*4+3] - mu) * rs * CG[q].w + CBB[q].w, 0.f);
        }
        // 4 x b64 granule writes, XOR-swizzled -> 2 dwords/bank (conflict-free)
#pragma unroll
        for (int q = 0; q < 4; ++q) {
          const int lg = q ^ s4;                       // logical granule in lane's window
          const int ks = (g16 * 2 + (lg >> 1)) & 3;    // k-subchunk within unit
          int slot = ((p >> 4) * 8 + (g16 >> 1)) * 64 + (p & 15) + 16 * ks;
          slot ^= ((slot >> 5) & 1) << 2;
          uint2 w;
          w.x = pk2(v[q*4+0], v[q*4+1]);
          w.y = pk2(v[q*4+2], v[q*4+3]);
          *(uint2*)&smA[(size_t)slot * 8 + (lg & 1) * 4] = w;
        }
      }
    }
  }
  __syncthreads();

  // ---- att GEMM pass: accT only, no barriers (attT frags straight from L2) ----
  f32x4 accT[8];
#pragma unroll
  for (int t = 0; t < 8; ++t) accT[t] = (f32x4){0.f, 0.f, 0.f, 0.f};
#pragma unroll 2
  for (int kc = 0; kc < 8; ++kc) {
    uint4 attf[8];
#pragma unroll
    for (int q = 0; q < 8; ++q)
      attf[q] = *(const uint4*)(attT + ((size_t)(q * 8 + kc) * 64 + lane) * 8);
    bf16x8 af = frag_ld(&smA[(size_t)((((wv * 8 + kc) * 64) + lane) ^ aswz) * 8]);
#pragma unroll
    for (int q = 0; q < 8; ++q) {
      bf16x8 bf = __builtin_bit_cast(bf16x8, attf[q]);
      accT[q] = __builtin_amdgcn_mfma_f32_16x16x32_bf16(af, bf, accT[q], 0, 0, 0);
    }
  }

  // prefetch ctx kc=0 B tiles into smX (smUV dead) — att epilogue covers the latency
#pragma unroll
  for (int i = 0; i < 4; ++i) {
    const int q = wv * 4 + i;
    glds16(ctxT + ((size_t)(q * 8 + 0) * 64 + lane) * 8, &smB[q * 512]);
  }

  // ---- att epilogue (accT dies here; writes att_s for this wave's own rows) ----
  {
    float ab[8], ag[8], abb[8], aw[8];
#pragma unroll
    for (int t = 0; t < 8; ++t) {
      const int col = t * 16 + cl;
      ab[t] = att1_b[col]; ag[t] = att_g[col]; abb[t] = att_bb[col]; aw[t] = att2_w[col];
    }
    const float b2 = att2_b[0];
#pragma unroll
    for (int r4 = 0; r4 < 4; ++r4) {
      float v[8], s = 0.f, sq = 0.f;
#pragma unroll
      for (int t = 0; t < 8; ++t) {
        v[t] = accT[t][r4] + ab[t];
        s += v[t]; sq += v[t] * v[t];
      }
      s = red16(s); sq = red16(sq);
      const float mu = s * (1.f / 128.f);
      const float rs = rsqrtf(sq * (1.f / 128.f) - mu * mu + 1e-5f);
      float d = 0.f;
#pragma unroll
      for (int t = 0; t < 8; ++t) {
        float h = tanh_fast((v[t] - mu) * rs * ag[t] + abb[t]);
        d = fmaf(h, aw[t], d);
      }
      d = red16(d);
      if (cl == 0) {
        const int r = wv * 16 + quad * 4 + r4;
        if (r < 56) att_s[r] = sigmoid_fast(d + b2);
      }
    }
  }

  // ---- ctx GEMM pass: glds-staged smB, 2 barriers per kc (measured-best) ----
  f32x4 accC[16];
#pragma unroll
  for (int t = 0; t < 16; ++t) accC[t] = (f32x4){0.f, 0.f, 0.f, 0.f};
  for (int kc = 0; kc < 8; ++kc) {
    __syncthreads();                // smB(kc) ready (kc0 prefetched pre-epilogue)
    bf16x8 af = frag_ld(&smA[(size_t)((((wv * 8 + kc) * 64) + lane) ^ aswz) * 8]);
#pragma unroll
    for (int q = 0; q < 16; ++q) {
      bf16x8 bf = frag_ld(&smB[(q * 64 + lane) * 8]);
      accC[q] = __builtin_amdgcn_mfma_f32_16x16x32_bf16(af, bf, accC[q], 0, 0, 0);
    }
    __syncthreads();                // all reads of smB(kc) + (kc==7) all smA reads done
    if (kc < 7) {
#pragma unroll
      for (int i = 0; i < 4; ++i) {
        const int q = wv * 4 + i;
        glds16(ctxT + ((size_t)(q * 8 + kc + 1) * 64 + lane) * 8, &smB[q * 512]);
      }
    }
  }

  // ---- ctx epilogue: LN -> relu -> * att -> bf16 into smS (stride 264) ----
  u16* smS = smA;
  {
    float cb[16], cg[16], cbb[16];
#pragma unroll
    for (int t = 0; t < 16; ++t) {
      const int col = t * 16 + cl;
      cb[t] = ctx_b[col]; cg[t] = ctx_g[col]; cbb[t] = ctx_bb[col];
    }
#pragma unroll
    for (int r4 = 0; r4 < 4; ++r4) {
      float v[16], s = 0.f, sq = 0.f;
#pragma unroll
      for (int t = 0; t < 16; ++t) {
        v[t] = accC[t][r4] + cb[t];
        s += v[t]; sq += v[t] * v[t];
      }
      s = red16(s); sq = red16(sq);
      const float mu = s * (1.f / 256.f);
      const float rs = rsqrtf(sq * (1.f / 256.f) - mu * mu + 1e-5f);
      const int r = wv * 16 + quad * 4 + r4;
      if (r < 56) {
        const float ap = att_s[r];
#pragma unroll
        for (int t = 0; t < 16; ++t) {
          const int col = t * 16 + cl;
          float o = fmaxf((v[t] - mu) * rs * cg[t] + cbb[t], 0.f) * ap;
          smS[r * 264 + col] = to_bf16(o);
        }
      }
    }
  }
  __syncthreads();   // effect reads smS across all waves' writes

  // ---- effect[i][c] = sum over 7 partners -> bf16 ----
  const int c = tid;
#pragma unroll
  for (int i = 0; i < 8; ++i) {
    float s = 0.f;
#pragma unroll
    for (int t2 = 0; t2 < 7; ++t2) s += from_bf16(smS[(i * 7 + t2) * 264 + c]);
    effb[(size_t)(g * 8 + i) * FC + c] = to_bf16(s);
  }
}

// ============ k_out: out = [s1|effect|x] @ out_w + out_b (fp32, x2) ============
// round-7 passing form: tile 32 rows x 256 cols; grid (512); K=1536 in pairs
__global__ __launch_bounds__(256) void k_out(
    const u16* __restrict__ s1b, const u16* __restrict__ effb,
    const float* __restrict__ x, const u16* __restrict__ outT,
    const float* __restrict__ out_b, float* __restrict__ out, int dup)
{
  __shared__ __align__(16) u16 smA[2][2 * 64 * 8];    // 2 x 2 KB (32 rows x 32 k)
  __shared__ __align__(16) u16 smB[2][16 * 64 * 8];   // 2 x 16 KB (256 cols x 32 k)
  const int tid = threadIdx.x, wv = tid >> 6, lane = tid & 63;
  const int cl = lane & 15, quad = lane >> 4;
  const int row0 = blockIdx.x * 32;
  const int rw = wv >> 1;          // row-tile 0..1 (16 rows)
  const int cw = wv & 1;           // col-half 0..1 (128 cols)
  f32x4 acc[8];
#pragma unroll
  for (int u = 0; u < 8; ++u) acc[u] = (f32x4){0.f, 0.f, 0.f, 0.f};

  for (int kk = 0; kk < 24; ++kk) {
    const int kc0 = kk * 2;
    __syncthreads();
    if (kc0 < 16) {
      // A: wave stages unit (p = wv>>1, u = wv&1) via glds — 4 waves cover 2p x 2u
      const int p = wv >> 1, u = wv & 1;
      const int kc = kc0 + p;
      const u16* base = (kc < 8) ? s1b : effb;
      const int kof = (kc & 7) * 32;
      glds16(base + (size_t)(row0 + u * 16 + (lane & 15)) * FC + kof + (lane >> 4) * 8,
             &smA[p][u * 512]);
    } else {
      // x: fp32 -> bf16, thread t stages (p = t>>7, unit u = (t&127)>>6, l = t&63)
      const int p = tid >> 7, lu = tid & 127;
      const int kc = kc0 + p;
      const int u = lu >> 6, l = lu & 63;
      const float* src = x + (size_t)(row0 + u * 16 + (l & 15)) * MX
                           + (kc - 16) * 32 + (l >> 4) * 8;
      float4 a = *(const float4*)src, b = *(const float4*)(src + 4);
      uint4 w; w.x = pk2(a.x, a.y); w.y = pk2(a.z, a.w); w.z = pk2(b.x, b.y); w.w = pk2(b.z, b.w);
      *(uint4*)&smA[p][(size_t)(u * 64 + l) * 8] = w;
    }
#pragma unroll
    for (int p = 0; p < 2; ++p)
#pragma unroll
      for (int i = 0; i < 4; ++i) {
        const int u = wv * 4 + i;                    // 0..15 col-units
        glds16(outT + ((size_t)(u * 48 + kc0 + p) * 64 + lane) * 8, &smB[p][u * 512]);
      }
    __syncthreads();
#pragma unroll
    for (int p = 0; p < 2; ++p) {
      bf16x8 af = frag_ld(&smA[p][(rw * 64 + lane) * 8]);
#pragma unroll
      for (int i = 0; i < 8; ++i) {
        bf16x8 bf = frag_ld(&smB[p][((cw * 8 + i) * 64 + lane) * 8]);
        acc[i] = __builtin_amdgcn_mfma_f32_16x16x32_bf16(af, bf, acc[i], 0, 0, 0);
      }
    }
  }
  float bias[8];
#pragma unroll
  for (int i = 0; i < 8; ++i) bias[i] = out_b[cw * 128 + i * 16 + cl];
#pragma unroll
  for (int r4 = 0; r4 < 4; ++r4) {
    const int row = row0 + rw * 16 + quad * 4 + r4;
#pragma unroll
    for (int i = 0; i < 8; ++i) {
      const float o = acc[i][r4] + bias[i];
      const size_t off = (size_t)row * FC + cw * 128 + i * 16 + cl;
      out[off] = o;
      if (dup) out[(size_t)NROW * FC + off] = o;
    }
  }
}

extern "C" void kernel_launch(void* const* d_in, const int* in_sizes, int n_in,
                              void* d_out, int out_size, void* d_ws, size_t ws_size,
                              hipStream_t stream) {
  const float* x      = (const float*)d_in[0];
  const float* state  = (const float*)d_in[1];
  const float* enc_w  = (const float*)d_in[2];
  const float* enc_b  = (const float*)d_in[3];
  const float* enc_g  = (const float*)d_in[4];
  const float* enc_bb = (const float*)d_in[5];
  const float* core_w = (const float*)d_in[6];
  const float* core_b = (const float*)d_in[7];
  const float* core_g = (const float*)d_in[8];
  const float* core_bb= (const float*)d_in[9];
  const float* ctx_w  = (const float*)d_in[10];
  const float* ctx_b  = (const float*)d_in[11];
  const float* ctx_g  = (const float*)d_in[12];
  const float* ctx_bb = (const float*)d_in[13];
  const float* att1_w = (const float*)d_in[14];
  const float* att1_b = (const float*)d_in[15];
  const float* att_g  = (const float*)d_in[16];
  const float* att_bb = (const float*)d_in[17];
  const float* att2_w = (const float*)d_in[18];
  const float* att2_b = (const float*)d_in[19];
  const float* out_w  = (const float*)d_in[20];
  const float* out_b  = (const float*)d_in[21];

  char* ws = (char*)d_ws;
  // UV region (first 32 MB) now unused — k_uv fused into k_pair (v8)
  u16* s1b   = (u16*)(ws + 33554432);               //  8,388,608 B
  u16* effb  = (u16*)(ws + 41943040);               //  8,388,608 B
  u16* encT  = (u16*)(ws + 50331648);               //    262,144 B
  u16* uvT   = (u16*)(ws + 50593792);               //    262,144 B
  u16* ctxT  = (u16*)(ws + 50855936);               //    131,072 B
  u16* attT  = (u16*)(ws + 50987008);               //     65,536 B
  u16* outT  = (u16*)(ws + 51052544);               //    786,432 B
  float* out = (float*)d_out;
  const int dup = (out_size >= 2 * NROW * FC) ? 1 : 0;

  k_prep<<<dim3(368), 256, 0, stream>>>(enc_w, core_w, ctx_w, att1_w, out_w,
                                        encT, uvT, ctxT, attT, outT);
  k_enc<<<dim3(NROW / 32), 256, 0, stream>>>(state, encT, enc_b, enc_g, enc_bb, s1b);
  k_pair<<<dim3(NGRP), 256, 0, stream>>>(s1b, uvT, core_b, core_g, core_bb,
                                         ctxT, ctx_b, ctx_g, ctx_bb,
                                         attT, att1_b, att_g, att_bb,
                                         att2_w, att2_b, effb);
  k_out<<<dim3(NROW / 32), 256, 0, stream>>>(s1b, effb, x, outT, out_b, out, dup);
}

// Round 9
// 283.701 us; speedup vs baseline: 1.0401x; 1.0401x over previous
//
#include <hip/hip_runtime.h>
#include <stdint.h>

#define FC    256
#define HH    512
#define MX    1024
#define LASTN 128
#define NROW  16384
#define NGRP  2048

typedef unsigned short u16;
typedef __bf16 bf16x8 __attribute__((ext_vector_type(8)));
typedef float  f32x4  __attribute__((ext_vector_type(4)));

__device__ __forceinline__ float red16(float v) {
#pragma unroll
  for (int m = 1; m < 16; m <<= 1) v += __shfl_xor(v, m);
  return v;
}
// reduce across the 16 lanes sharing (lane & 3)
__device__ __forceinline__ float red16hi(float v) {
#pragma unroll
  for (int m = 4; m < 64; m <<= 1) v += __shfl_xor(v, m);
  return v;
}
__device__ __forceinline__ u16 to_bf16(float f) {
  unsigned u = __float_as_uint(f);
  return (u16)((u + 0x8000u) >> 16);
}
__device__ __forceinline__ float from_bf16(u16 s) {
  return __uint_as_float(((unsigned)s) << 16);
}
__device__ __forceinline__ uint32_t pk2(float a, float b) {
  return (uint32_t)to_bf16(a) | ((uint32_t)to_bf16(b) << 16);
}
__device__ __forceinline__ float tanh_fast(float x) {
  float e = __expf(2.f * x);
  return __fdividef(e - 1.f, e + 1.f);
}
__device__ __forceinline__ float sigmoid_fast(float x) {
  return __fdividef(1.f, 1.f + __expf(-x));
}
// async global->LDS, 16B per lane; LDS dest = wave-uniform base + lane*16
__device__ __forceinline__ void glds16(const void* g, void* l) {
  __builtin_amdgcn_global_load_lds(
      (__attribute__((address_space(1))) uint32_t*)g,
      (__attribute__((address_space(3))) uint32_t*)l, 16, 0, 0);
}
__device__ __forceinline__ bf16x8 frag_ld(const u16* p) {
  return __builtin_bit_cast(bf16x8, *(const uint4*)p);
}

// ============ k_prep: weights -> fragment-ordered bf16 global layout ============
// unit id = (u*NKC + kc)*64 + l ; contents j=0..7: W[kc*32+(l>>4)*8+j][u*16+(l&15)]
__global__ __launch_bounds__(256) void k_prep(
    const float* __restrict__ enc_w, const float* __restrict__ core_w,
    const float* __restrict__ ctx_w, const float* __restrict__ att1_w,
    const float* __restrict__ out_w,
    u16* __restrict__ encT, u16* __restrict__ uvT, u16* __restrict__ ctxT,
    u16* __restrict__ attT, u16* __restrict__ outT)
{
  const int bx = blockIdx.x, tid = threadIdx.x;
  const float* W; u16* D; int NKC, N, local; int uv = 0;
  if (bx < 64)       { W = enc_w;  D = encT; NKC = 16; N = 256; local = bx * 256 + tid; }
  else if (bx < 128) { W = core_w; D = uvT;  NKC = 8;  N = 256; local = (bx-64)*256 + tid; uv = 1; }
  else if (bx < 160) { W = ctx_w;  D = ctxT; NKC = 8;  N = 256; local = (bx-128)*256 + tid; }
  else if (bx < 176) { W = att1_w; D = attT; NKC = 8;  N = 128; local = (bx-160)*256 + tid; }
  else               { W = out_w;  D = outT; NKC = 48; N = 256; local = (bx-176)*256 + tid; }
  const int l  = local & 63;
  const int kc = (local >> 6) % NKC;
  const int u  = (local >> 6) / NKC;
  const int n  = u * 16 + (l & 15);
  const int k0 = kc * 32 + (l >> 4) * 8;
  float f[8];
#pragma unroll
  for (int j = 0; j < 8; ++j) {
    const int k = k0 + j;
    if (uv) f[j] = (n < 256) ? W[(size_t)k * 256 + n] : W[(size_t)(256 + k) * 256 + (n - 256)];
    else    f[j] = W[(size_t)k * N + n];
  }
  uint4 w;
  w.x = pk2(f[0], f[1]); w.y = pk2(f[2], f[3]);
  w.z = pk2(f[4], f[5]); w.w = pk2(f[6], f[7]);
  *(uint4*)&D[(size_t)local * 8] = w;
}

// ============ k_enc: s1 = relu(LN(state @ enc_w + b)) -> s1b ============
// v9: BK=128 (4 kc per stage) — barriers 16->8, 32 MFMA/wave per stage.
// LDS 72 KB; grid 512 = 2 blocks/CU (grid-limited, so no occupancy cost).
__global__ __launch_bounds__(256) void k_enc(
    const float* __restrict__ state, const u16* __restrict__ encT,
    const float* __restrict__ enc_b, const float* __restrict__ enc_g,
    const float* __restrict__ enc_bb, u16* __restrict__ s1b)
{
  __shared__ __align__(16) u16 smA[4][128 * 8];     // 4 x 2 KB
  __shared__ __align__(16) u16 smB[4][16 * 64 * 8]; // 4 x 16 KB
  __shared__ float smP[2][2][16][2];
  const int tid = threadIdx.x, wv = tid >> 6, lane = tid & 63;
  const int cl = lane & 15, quad = lane >> 4;
  const int rb = wv >> 1, cb = wv & 1;
  const int row0 = blockIdx.x * 32;
  f32x4 acc[8];
#pragma unroll
  for (int u = 0; u < 8; ++u) acc[u] = (f32x4){0.f, 0.f, 0.f, 0.f};

  for (int kk = 0; kk < 4; ++kk) {
    __syncthreads();
    { // A: each thread stages 2 units (p = pp*2 + tid>>7), fp32 -> bf16
      const int lu = tid & 127;
      const int rblk = lu >> 6, ll = lu & 63;
#pragma unroll
      for (int pp = 0; pp < 2; ++pp) {
        const int p = pp * 2 + (tid >> 7);
        const int kc = kk * 4 + p;
        const float* src = state + (size_t)(row0 + rblk * 16 + (ll & 15)) * HH + kc * 32 + (ll >> 4) * 8;
        float4 a = *(const float4*)src, b = *(const float4*)(src + 4);
        uint4 w; w.x = pk2(a.x, a.y); w.y = pk2(a.z, a.w); w.z = pk2(b.x, b.y); w.w = pk2(b.z, b.w);
        *(uint4*)&smA[p][(size_t)lu * 8] = w;
      }
    }
#pragma unroll
    for (int p = 0; p < 4; ++p)
#pragma unroll
      for (int i = 0; i < 4; ++i) {
        const int u = wv * 4 + i;
        glds16(encT + ((size_t)(u * 16 + kk * 4 + p) * 64 + lane) * 8, &smB[p][u * 512]);
      }
    __syncthreads();
#pragma unroll
    for (int p = 0; p < 4; ++p) {
      bf16x8 af = frag_ld(&smA[p][(rb * 64 + lane) * 8]);
#pragma unroll
      for (int u = 0; u < 8; ++u) {
        bf16x8 bf = frag_ld(&smB[p][((cb * 8 + u) * 64 + lane) * 8]);
        acc[u] = __builtin_amdgcn_mfma_f32_16x16x32_bf16(af, bf, acc[u], 0, 0, 0);
      }
    }
  }
  float bias[8], gg[8], bb[8];
#pragma unroll
  for (int u = 0; u < 8; ++u) {
    const int col = cb * 128 + u * 16 + cl;
    bias[u] = enc_b[col]; gg[u] = enc_g[col]; bb[u] = enc_bb[col];
  }
  float vv[4][8];
#pragma unroll
  for (int r4 = 0; r4 < 4; ++r4) {
    float s = 0.f, sq = 0.f;
#pragma unroll
    for (int u = 0; u < 8; ++u) {
      float v = acc[u][r4] + bias[u];
      vv[r4][u] = v; s += v; sq += v * v;
    }
    s = red16(s); sq = red16(sq);
    if (cl == 0) { smP[cb][rb][quad * 4 + r4][0] = s; smP[cb][rb][quad * 4 + r4][1] = sq; }
  }
  __syncthreads();
#pragma unroll
  for (int r4 = 0; r4 < 4; ++r4) {
    const int rr = quad * 4 + r4;
    const float S  = smP[0][rb][rr][0] + smP[1][rb][rr][0];
    const float SQ = smP[0][rb][rr][1] + smP[1][rb][rr][1];
    const float mu = S * (1.f / 256.f);
    const float rs = rsqrtf(SQ * (1.f / 256.f) - mu * mu + 1e-5f);
    const int row = row0 + rb * 16 + rr;
#pragma unroll
    for (int u = 0; u < 8; ++u) {
      float o = fmaxf((vv[r4][u] - mu) * rs * gg[u] + bb[u], 0.f);
      s1b[(size_t)row * FC + cb * 128 + u * 16 + cl] = to_bf16(o);
    }
  }
}

// ============ k_uv: UV = s1 @ [coreW_u | coreW_v] (fp32 out) ============
// round-7 passing form: tile 64 x 128; grid (256, 4); K=256 in pairs
__global__ __launch_bounds__(256) void k_uv(
    const u16* __restrict__ s1b, const u16* __restrict__ uvT,
    float* __restrict__ UV)
{
  __shared__ __align__(16) u16 smA[2][4 * 64 * 8];   // 2 x 4 KB
  __shared__ __align__(16) u16 smB[2][8 * 64 * 8];   // 2 x 8 KB
  const int tid = threadIdx.x, wv = tid >> 6, lane = tid & 63;
  const int cl = lane & 15, quad = lane >> 4;
  const int row0 = blockIdx.x * 64;
  const int nb = blockIdx.y;                         // 0..3 over 512 cols
  f32x4 acc[8];
#pragma unroll
  for (int u = 0; u < 8; ++u) acc[u] = (f32x4){0.f, 0.f, 0.f, 0.f};

  for (int kk = 0; kk < 4; ++kk) {
    __syncthreads();
#pragma unroll
    for (int p = 0; p < 2; ++p) {
      const int kc = kk * 2 + p;
      glds16(s1b + (size_t)(row0 + wv * 16 + (lane & 15)) * FC + kc * 32 + (lane >> 4) * 8,
             &smA[p][wv * 512]);
#pragma unroll
      for (int i = 0; i < 2; ++i) {
        const int u = wv * 2 + i;
        glds16(uvT + ((size_t)((nb * 8 + u) * 8 + kc) * 64 + lane) * 8, &smB[p][u * 512]);
      }
    }
    __syncthreads();
#pragma unroll
    for (int p = 0; p < 2; ++p) {
      bf16x8 af = frag_ld(&smA[p][(wv * 64 + lane) * 8]);
#pragma unroll
      for (int u = 0; u < 8; ++u) {
        bf16x8 bf = frag_ld(&smB[p][(u * 64 + lane) * 8]);
        acc[u] = __builtin_amdgcn_mfma_f32_16x16x32_bf16(af, bf, acc[u], 0, 0, 0);
      }
    }
  }
#pragma unroll
  for (int r4 = 0; r4 < 4; ++r4) {
    const int row = row0 + wv * 16 + quad * 4 + r4;
#pragma unroll
    for (int u = 0; u < 8; ++u)
      UV[(size_t)row * 512 + nb * 128 + u * 16 + cl] = acc[u][r4];
  }
}

// ============ k_pair: fused core-build + att/ctx GEMM passes + epilogues ============
// round-6/7 passing form (measured 78.3us): v2 structure + ctx kc=0 prefetch hoist.
__global__ __launch_bounds__(256, 3) void k_pair(
    const float* __restrict__ UV, const float* __restrict__ core_b,
    const float* __restrict__ core_g, const float* __restrict__ core_bb,
    const u16* __restrict__ ctxT, const float* __restrict__ ctx_b,
    const float* __restrict__ ctx_g, const float* __restrict__ ctx_bb,
    const u16* __restrict__ attT, const float* __restrict__ att1_b,
    const float* __restrict__ att_g, const float* __restrict__ att_bb,
    const float* __restrict__ att2_w, const float* __restrict__ att2_b,
    u16* __restrict__ effb)
{
  __shared__ __align__(16) u16 smA[2048 * 8];     // 32 KB frag-ordered core; reused as smS
  __shared__ __align__(16) u16 smX[16 * 64 * 8];  // 16 KB: UV staging, then ctx B staging
  __shared__ float att_s[64];
  float* smUV = (float*)smX;                      // 16 rows x 256 f32 (core-build phase)
  u16*   smB  = smX;                              // 16 units x 1 KB (ctx phase)
  const int g = blockIdx.x;
  const int tid = threadIdx.x, wv = tid >> 6, lane = tid & 63;
  const int cl = lane & 15, quad = lane >> 4;
  const int aswz = ((lane >> 5) & 1) << 2;        // A-frag read swizzle (bit5 -> bit2)

  // prefetch this group's 16 UV rows into LDS (async, overlapped with smA zeroing)
#pragma unroll
  for (int i = 0; i < 4; ++i) {
    const int r = wv * 4 + i;                 // 0..15
    const int row = g * 8 + (r & 7);
    const int half = r >> 3;
    glds16(UV + (size_t)row * 512 + half * 256 + lane * 4, &smUV[r * 256]);
  }
  // zero A (covers pad rows 56..63; swizzle is a bijection so full zero is safe)
#pragma unroll
  for (int i = 0; i < 8; ++i)
    *(uint4*)&smA[(size_t)(tid + i * 256) * 8] = (uint4){0u, 0u, 0u, 0u};
  __syncthreads();   // drains glds too

  // ---- build core from LDS: 4 passes; wave covers 4 rows x 16 col-groups ----
  {
    const int s4  = lane & 3;        // row-within-4 (varies inside each 16-lane quarter)
    const int g16 = lane >> 2;       // column group 0..15
    const int c0  = g16 * 16;
    float4 CB[4], CG[4], CBB[4];     // CB[q] belongs to granule (q^s4) of this lane's window
#pragma unroll
    for (int q = 0; q < 4; ++q) {
      const int cq = c0 + ((q ^ s4) << 2);
      CB[q]  = *(const float4*)&core_b[cq];
      CG[q]  = *(const float4*)&core_g[cq];
      CBB[q] = *(const float4*)&core_bb[cq];
    }
#pragma unroll
    for (int it = 0; it < 4; ++it) {
      const int p = it * 16 + wv * 4 + s4;   // wave-uniform branch: 56 = it3,wv2,s4=0
      if (p < 56) {
        const int i = p / 7, t = p - i * 7;
        const int j = t + (t >= i ? 1 : 0);
        const float* uA = &smUV[i * 256 + c0];
        const float* vB = &smUV[(8 + j) * 256 + c0];
        float v[16];
        float s = 0.f, sq = 0.f;
#pragma unroll
        for (int q = 0; q < 4; ++q) {
          const int qo = (q ^ s4) << 2;      // XOR-rotated chunk order: conflict-free reads
          float4 ua = *(const float4*)(uA + qo);
          float4 vb = *(const float4*)(vB + qo);
          float x0 = ua.x + vb.x + CB[q].x, x1 = ua.y + vb.y + CB[q].y;
          float x2 = ua.z + vb.z + CB[q].z, x3 = ua.w + vb.w + CB[q].w;
          v[q*4+0] = x0; v[q*4+1] = x1; v[q*4+2] = x2; v[q*4+3] = x3;
          s += x0 + x1 + x2 + x3;
          sq += x0*x0 + x1*x1 + x2*x2 + x3*x3;
        }
        s = red16hi(s); sq = red16hi(sq);
        const float mu = s * (1.f / 256.f);
        const float rs = rsqrtf(sq * (1.f / 256.f) - mu * mu + 1e-5f);
#pragma unroll
        for (int q = 0; q < 4; ++q) {
          v[q*4+0] = fmaxf((v[q*4+0] - mu) * rs * CG[q].x + CBB[q].x, 0.f);
          v[q*4+1] = fmaxf((v[q*4+1] - mu) * rs * CG[q].y + CBB[q].y, 0.f);
          v[q*4+2] = fmaxf((v[q*4+2] - mu) * rs * CG[q].z + CBB[q].z, 0.f);
          v[q*4+3] = fmaxf((v[q*4+3] - mu) * rs * CG[q].w + CBB[q].w, 0.f);
        }
        // 4 x b64 granule writes, XOR-swizzled -> 2 dwords/bank (conflict-free)
#pragma unroll
        for (int q = 0; q < 4; ++q) {
          const int lg = q ^ s4;                       // logical granule in lane's window
          const int ks = (g16 * 2 + (lg >> 1)) & 3;    // k-subchunk within unit
          int slot = ((p >> 4) * 8 + (g16 >> 1)) * 64 + (p & 15) + 16 * ks;
          slot ^= ((slot >> 5) & 1) << 2;
          uint2 w;
          w.x = pk2(v[q*4+0], v[q*4+1]);
          w.y = pk2(v[q*4+2], v[q*4+3]);
          *(uint2*)&smA[(size_t)slot * 8 + (lg & 1) * 4] = w;
        }
      }
    }
  }
  __syncthreads();

  // ---- att GEMM pass: accT only, no barriers (attT frags straight from L2) ----
  f32x4 accT[8];
#pragma unroll
  for (int t = 0; t < 8; ++t) accT[t] = (f32x4){0.f, 0.f, 0.f, 0.f};
#pragma unroll 2
  for (int kc = 0; kc < 8; ++kc) {
    uint4 attf[8];
#pragma unroll
    for (int q = 0; q < 8; ++q)
      attf[q] = *(const uint4*)(attT + ((size_t)(q * 8 + kc) * 64 + lane) * 8);
    bf16x8 af = frag_ld(&smA[(size_t)((((wv * 8 + kc) * 64) + lane) ^ aswz) * 8]);
#pragma unroll
    for (int q = 0; q < 8; ++q) {
      bf16x8 bf = __builtin_bit_cast(bf16x8, attf[q]);
      accT[q] = __builtin_amdgcn_mfma_f32_16x16x32_bf16(af, bf, accT[q], 0, 0, 0);
    }
  }

  // prefetch ctx kc=0 B tiles into smX (smUV dead) — att epilogue covers the latency
#pragma unroll
  for (int i = 0; i < 4; ++i) {
    const int q = wv * 4 + i;
    glds16(ctxT + ((size_t)(q * 8 + 0) * 64 + lane) * 8, &smB[q * 512]);
  }

  // ---- att epilogue (accT dies here; writes att_s for this wave's own rows) ----
  {
    float ab[8], ag[8], abb[8], aw[8];
#pragma unroll
    for (int t = 0; t < 8; ++t) {
      const int col = t * 16 + cl;
      ab[t] = att1_b[col]; ag[t] = att_g[col]; abb[t] = att_bb[col]; aw[t] = att2_w[col];
    }
    const float b2 = att2_b[0];
#pragma unroll
    for (int r4 = 0; r4 < 4; ++r4) {
      float v[8], s = 0.f, sq = 0.f;
#pragma unroll
      for (int t = 0; t < 8; ++t) {
        v[t] = accT[t][r4] + ab[t];
        s += v[t]; sq += v[t] * v[t];
      }
      s = red16(s); sq = red16(sq);
      const float mu = s * (1.f / 128.f);
      const float rs = rsqrtf(sq * (1.f / 128.f) - mu * mu + 1e-5f);
      float d = 0.f;
#pragma unroll
      for (int t = 0; t < 8; ++t) {
        float h = tanh_fast((v[t] - mu) * rs * ag[t] + abb[t]);
        d = fmaf(h, aw[t], d);
      }
      d = red16(d);
      if (cl == 0) {
        const int r = wv * 16 + quad * 4 + r4;
        if (r < 56) att_s[r] = sigmoid_fast(d + b2);
      }
    }
  }

  // ---- ctx GEMM pass: glds-staged smB, 2 barriers per kc (measured-best) ----
  f32x4 accC[16];
#pragma unroll
  for (int t = 0; t < 16; ++t) accC[t] = (f32x4){0.f, 0.f, 0.f, 0.f};
  for (int kc = 0; kc < 8; ++kc) {
    __syncthreads();                // smB(kc) ready (kc0 prefetched pre-epilogue)
    bf16x8 af = frag_ld(&smA[(size_t)((((wv * 8 + kc) * 64) + lane) ^ aswz) * 8]);
#pragma unroll
    for (int q = 0; q < 16; ++q) {
      bf16x8 bf = frag_ld(&smB[(q * 64 + lane) * 8]);
      accC[q] = __builtin_amdgcn_mfma_f32_16x16x32_bf16(af, bf, accC[q], 0, 0, 0);
    }
    __syncthreads();                // all reads of smB(kc) + (kc==7) all smA reads done
    if (kc < 7) {
#pragma unroll
      for (int i = 0; i < 4; ++i) {
        const int q = wv * 4 + i;
        glds16(ctxT + ((size_t)(q * 8 + kc + 1) * 64 + lane) * 8, &smB[q * 512]);
      }
    }
  }

  // ---- ctx epilogue: LN -> relu -> * att -> bf16 into smS (stride 264) ----
  u16* smS = smA;
  {
    float cb[16], cg[16], cbb[16];
#pragma unroll
    for (int t = 0; t < 16; ++t) {
      const int col = t * 16 + cl;
      cb[t] = ctx_b[col]; cg[t] = ctx_g[col]; cbb[t] = ctx_bb[col];
    }
#pragma unroll
    for (int r4 = 0; r4 < 4; ++r4) {
      float v[16], s = 0.f, sq = 0.f;
#pragma unroll
      for (int t = 0; t < 16; ++t) {
        v[t] = accC[t][r4] + cb[t];
        s += v[t]; sq += v[t] * v[t];
      }
      s = red16(s); sq = red16(sq);
      const float mu = s * (1.f / 256.f);
      const float rs = rsqrtf(sq * (1.f / 256.f) - mu * mu + 1e-5f);
      const int r = wv * 16 + quad * 4 + r4;
      if (r < 56) {
        const float ap = att_s[r];
#pragma unroll
        for (int t = 0; t < 16; ++t) {
          const int col = t * 16 + cl;
          float o = fmaxf((v[t] - mu) * rs * cg[t] + cbb[t], 0.f) * ap;
          smS[r * 264 + col] = to_bf16(o);
        }
      }
    }
  }
  __syncthreads();   // effect reads smS across all waves' writes

  // ---- effect[i][c] = sum over 7 partners -> bf16 ----
  const int c = tid;
#pragma unroll
  for (int i = 0; i < 8; ++i) {
    float s = 0.f;
#pragma unroll
    for (int t2 = 0; t2 < 7; ++t2) s += from_bf16(smS[(i * 7 + t2) * 264 + c]);
    effb[(size_t)(g * 8 + i) * FC + c] = to_bf16(s);
  }
}

// ============ k_out: out = [s1|effect|x] @ out_w + out_b (fp32, x2) ============
// v9: tile 32 x 256, grid (512), BK=128 (4 kc per stage) — barriers 48->24,
// 32 MFMA/wave per stage. LDS 72 KB; grid-limited 2 blocks/CU (no occupancy cost).
__global__ __launch_bounds__(256) void k_out(
    const u16* __restrict__ s1b, const u16* __restrict__ effb,
    const float* __restrict__ x, const u16* __restrict__ outT,
    const float* __restrict__ out_b, float* __restrict__ out, int dup)
{
  __shared__ __align__(16) u16 smA[4][2 * 64 * 8];    // 4 x 2 KB (32 rows x 32 k)
  __shared__ __align__(16) u16 smB[4][16 * 64 * 8];   // 4 x 16 KB (256 cols x 32 k)
  const int tid = threadIdx.x, wv = tid >> 6, lane = tid & 63;
  const int cl = lane & 15, quad = lane >> 4;
  const int row0 = blockIdx.x * 32;
  const int rw = wv >> 1;          // row-tile 0..1 (16 rows)
  const int cw = wv & 1;           // col-half 0..1 (128 cols)
  f32x4 acc[8];
#pragma unroll
  for (int u = 0; u < 8; ++u) acc[u] = (f32x4){0.f, 0.f, 0.f, 0.f};

  for (int kk = 0; kk < 12; ++kk) {
    const int kc0 = kk * 4;
    __syncthreads();
    if (kc0 < 16) {
      // A: wave wv stages kc = kc0 + wv for both row-units (2 glds)
      const int p = wv;
      const int kc = kc0 + p;
      const u16* base = (kc < 8) ? s1b : effb;
      const int kof = (kc & 7) * 32;
#pragma unroll
      for (int u = 0; u < 2; ++u)
        glds16(base + (size_t)(row0 + u * 16 + (lane & 15)) * FC + kof + (lane >> 4) * 8,
               &smA[p][u * 512]);
    } else {
      // x: fp32 -> bf16; thread t stages 2 of 4 kc (p = pp*2 + t>>7)
      const int lu = tid & 127;
      const int u = lu >> 6, l = lu & 63;
#pragma unroll
      for (int pp = 0; pp < 2; ++pp) {
        const int p = pp * 2 + (tid >> 7);
        const int kc = kc0 + p;
        const float* src = x + (size_t)(row0 + u * 16 + (l & 15)) * MX
                             + (kc - 16) * 32 + (l >> 4) * 8;
        float4 a = *(const float4*)src, b = *(const float4*)(src + 4);
        uint4 w; w.x = pk2(a.x, a.y); w.y = pk2(a.z, a.w); w.z = pk2(b.x, b.y); w.w = pk2(b.z, b.w);
        *(uint4*)&smA[p][(size_t)(u * 64 + l) * 8] = w;
      }
    }
#pragma unroll
    for (int p = 0; p < 4; ++p)
#pragma unroll
      for (int i = 0; i < 4; ++i) {
        const int u = wv * 4 + i;                    // 0..15 col-units
        glds16(outT + ((size_t)(u * 48 + kc0 + p) * 64 + lane) * 8, &smB[p][u * 512]);
      }
    __syncthreads();
#pragma unroll
    for (int p = 0; p < 4; ++p) {
      bf16x8 af = frag_ld(&smA[p][(rw * 64 + lane) * 8]);
#pragma unroll
      for (int i = 0; i < 8; ++i) {
        bf16x8 bf = frag_ld(&smB[p][((cw * 8 + i) * 64 + lane) * 8]);
        acc[i] = __builtin_amdgcn_mfma_f32_16x16x32_bf16(af, bf, acc[i], 0, 0, 0);
      }
    }
  }
  float bias[8];
#pragma unroll
  for (int i = 0; i < 8; ++i) bias[i] = out_b[cw * 128 + i * 16 + cl];
#pragma unroll
  for (int r4 = 0; r4 < 4; ++r4) {
    const int row = row0 + rw * 16 + quad * 4 + r4;
#pragma unroll
    for (int i = 0; i < 8; ++i) {
      const float o = acc[i][r4] + bias[i];
      const size_t off = (size_t)row * FC + cw * 128 + i * 16 + cl;
      out[off] = o;
      if (dup) out[(size_t)NROW * FC + off] = o;
    }
  }
}

extern "C" void kernel_launch(void* const* d_in, const int* in_sizes, int n_in,
                              void* d_out, int out_size, void* d_ws, size_t ws_size,
                              hipStream_t stream) {
  const float* x      = (const float*)d_in[0];
  const float* state  = (const float*)d_in[1];
  const float* enc_w  = (const float*)d_in[2];
  const float* enc_b  = (const float*)d_in[3];
  const float* enc_g  = (const float*)d_in[4];
  const float* enc_bb = (const float*)d_in[5];
  const float* core_w = (const float*)d_in[6];
  const float* core_b = (const float*)d_in[7];
  const float* core_g = (const float*)d_in[8];
  const float* core_bb= (const float*)d_in[9];
  const float* ctx_w  = (const float*)d_in[10];
  const float* ctx_b  = (const float*)d_in[11];
  const float* ctx_g  = (const float*)d_in[12];
  const float* ctx_bb = (const float*)d_in[13];
  const float* att1_w = (const float*)d_in[14];
  const float* att1_b = (const float*)d_in[15];
  const float* att_g  = (const float*)d_in[16];
  const float* att_bb = (const float*)d_in[17];
  const float* att2_w = (const float*)d_in[18];
  const float* att2_b = (const float*)d_in[19];
  const float* out_w  = (const float*)d_in[20];
  const float* out_b  = (const float*)d_in[21];

  char* ws = (char*)d_ws;
  float* UV  = (float*)ws;                          // 33,554,432 B
  u16* s1b   = (u16*)(ws + 33554432);               //  8,388,608 B
  u16* effb  = (u16*)(ws + 41943040);               //  8,388,608 B
  u16* encT  = (u16*)(ws + 50331648);               //    262,144 B
  u16* uvT   = (u16*)(ws + 50593792);               //    262,144 B
  u16* ctxT  = (u16*)(ws + 50855936);               //    131,072 B
  u16* attT  = (u16*)(ws + 50987008);               //     65,536 B
  u16* outT  = (u16*)(ws + 51052544);               //    786,432 B
  float* out = (float*)d_out;
  const int dup = (out_size >= 2 * NROW * FC) ? 1 : 0;

  k_prep<<<dim3(368), 256, 0, stream>>>(enc_w, core_w, ctx_w, att1_w, out_w,
                                        encT, uvT, ctxT, attT, outT);
  k_enc<<<dim3(NROW / 32), 256, 0, stream>>>(state, encT, enc_b, enc_g, enc_bb, s1b);
  k_uv <<<dim3(NROW / 64, 4), 256, 0, stream>>>(s1b, uvT, UV);
  k_pair<<<dim3(NGRP), 256, 0, stream>>>(UV, core_b, core_g, core_bb,
                                         ctxT, ctx_b, ctx_g, ctx_bb,
                                         attT, att1_b, att_g, att_bb,
                                         att2_w, att2_b, effb);
  k_out<<<dim3(NROW / 32), 256, 0, stream>>>(s1b, effb, x, outT, out_b, out, dup);
}